// Round 1
// baseline (9275.676 us; speedup 1.0000x reference)
//
#include <hip/hip_runtime.h>
#include <math.h>

#define N   2048
#define NT  256

// stable logaddexp
__device__ __forceinline__ float lae(float a, float b) {
    float m  = fmaxf(a, b);
    float mn = fminf(a, b);
    return m + log1pf(expf(mn - m));
}

__global__ void __launch_bounds__(NT)
soft_spearman_kernel(const float* __restrict__ x1,
                     const float* __restrict__ x2,
                     float* __restrict__ out)
{
    __shared__ float s_key[N];   // sorted theta
    __shared__ int   s_idx[N];   // original index payload
    __shared__ float s_r1[N];    // ranks of x1 row (original order)
    __shared__ float s_ly[N];    // PAV lse_y
    __shared__ float s_lw[N];    // PAV lse_w
    __shared__ float s_sol[N];   // PAV sol
    __shared__ int   s_tgt[N];   // PAV target (block skip pointers), reused for head list
    __shared__ int   s_nb;
    __shared__ float s_red[NT / 64][5];

    const int row = blockIdx.x;
    const int tid = threadIdx.x;

    float S1 = 0.f, Q1 = 0.f, S2 = 0.f, Q2 = 0.f, P = 0.f;

    for (int phase = 0; phase < 2; ++phase) {
        const float* __restrict__ x = (phase == 0) ? x1 : x2;
        const size_t base = (size_t)row * N;

        // ---- load & scale (theta = x / EPS, EPS = 0.1) ----
        for (int j = tid; j < N; j += NT) {
            s_key[j] = x[base + j] * 10.0f;
            s_idx[j] = j;
        }
        __syncthreads();

        // ---- bitonic sort, descending by key, with index payload ----
        for (int k = 2; k <= N; k <<= 1) {
            for (int jj = k >> 1; jj > 0; jj >>= 1) {
                for (int i = tid; i < N; i += NT) {
                    int l = i ^ jj;
                    if (l > i) {
                        float ki = s_key[i], kl = s_key[l];
                        bool sw = ((i & k) == 0) ? (ki < kl) : (ki > kl);
                        if (sw) {
                            s_key[i] = kl; s_key[l] = ki;
                            int t = s_idx[i]; s_idx[i] = s_idx[l]; s_idx[l] = t;
                        }
                    }
                }
                __syncthreads();
            }
        }

        // ---- init PAV state (parallel) ----
        // logw[j] = log(n - j)  (log of [n, n-1, ..., 1])
        for (int j = tid; j < N; j += NT) {
            float y = s_key[j];
            float w = logf((float)(N - j));
            s_ly[j]  = y;
            s_lw[j]  = w;
            s_sol[j] = y - w;
            s_tgt[j] = j;
        }
        __syncthreads();

        // ---- PAV: literal port of fast-soft-sort isotonic_kl (serial, thread 0) ----
        if (tid == 0) {
            int i = 0;
            while (i < N) {
                int k = s_tgt[i] + 1;
                if (k >= N) break;                       // advance past end -> done
                if (s_sol[i] > s_sol[k]) { i = k; continue; }  // strictly decreasing: advance
                float sol_prev = s_sol[i];               // anchor value, FIXED for this run
                for (;;) {
                    // pool block k into block i
                    float ly = lae(s_ly[i], s_ly[k]);
                    float lw = lae(s_lw[i], s_lw[k]);
                    s_ly[i] = ly; s_lw[i] = lw; s_sol[i] = ly - lw;
                    int kn = s_tgt[k] + 1;               // next block head
                    if (kn >= N || sol_prev > s_sol[kn]) {
                        s_tgt[i] = kn - 1;               // head -> end
                        s_tgt[kn - 1] = i;               // end  -> head
                        if (i > 0) i = s_tgt[i - 1];     // backtrack to previous head
                        break;
                    }
                    k = kn;
                }
            }
            // ---- compact block heads into s_tgt[0..nb) (ascending) ----
            // safe in-place: head index h_j >= j, and we read s_tgt[h] before writing slot j
            int nb = 0, h = 0;
            while (h < N) {
                int e  = s_tgt[h];   // block end
                int hh = h;
                h = e + 1;
                s_tgt[nb++] = hh;
            }
            s_nb = nb;
        }
        __syncthreads();

        // ---- expand sol, compute ranks, scatter, accumulate moments ----
        const int nb = s_nb;
        for (int j = tid; j < N; j += NT) {
            // binary search: largest b with head[b] <= j
            int lo = 0, hi = nb - 1;
            while (lo < hi) {
                int mid = (lo + hi + 1) >> 1;
                if (s_tgt[mid] <= j) lo = mid; else hi = mid - 1;
            }
            float r = expf(s_key[j] - s_sol[s_tgt[lo]]);
            int   v = s_idx[j];
            if (phase == 0) {
                s_r1[v] = r;
                S1 += r; Q1 += r * r;
            } else {
                float a = s_r1[v];
                S2 += r; Q2 += r * r; P += a * r;
            }
        }
        __syncthreads();  // protect s_key/s_idx/s_tgt before next phase reuse
    }

    // ---- block reduction of the 5 moments ----
    #pragma unroll
    for (int off = 32; off > 0; off >>= 1) {
        S1 += __shfl_down(S1, off);
        Q1 += __shfl_down(Q1, off);
        S2 += __shfl_down(S2, off);
        Q2 += __shfl_down(Q2, off);
        P  += __shfl_down(P,  off);
    }
    const int wid = tid >> 6, lane = tid & 63;
    if (lane == 0) {
        s_red[wid][0] = S1; s_red[wid][1] = Q1; s_red[wid][2] = S2;
        s_red[wid][3] = Q2; s_red[wid][4] = P;
    }
    __syncthreads();
    if (tid == 0) {
        for (int w = 1; w < NT / 64; ++w) {
            S1 += s_red[w][0]; Q1 += s_red[w][1]; S2 += s_red[w][2];
            Q2 += s_red[w][3]; P  += s_red[w][4];
        }
        const float inv_n = 1.0f / (float)N;
        float num = P  - S1 * S2 * inv_n;
        float d1  = Q1 - S1 * S1 * inv_n;
        float d2  = Q2 - S2 * S2 * inv_n;
        out[row] = 1.0f - num / sqrtf(d1 * d2);
    }
}

extern "C" void kernel_launch(void* const* d_in, const int* in_sizes, int n_in,
                              void* d_out, int out_size, void* d_ws, size_t ws_size,
                              hipStream_t stream) {
    const float* x1 = (const float*)d_in[0];
    const float* x2 = (const float*)d_in[1];
    float* out = (float*)d_out;
    const int nrows = in_sizes[0] / N;   // 16*256 = 4096
    soft_spearman_kernel<<<nrows, NT, 0, stream>>>(x1, x2, out);
}

// Round 2
// 2557.296 us; speedup vs baseline: 3.6271x; 3.6271x over previous
//
#include <hip/hip_runtime.h>
#include <math.h>

#define N   2048
#define NT  256

// stable logaddexp
__device__ __forceinline__ float lae(float a, float b) {
    float m  = fmaxf(a, b);
    float mn = fminf(a, b);
    return m + log1pf(expf(mn - m));
}

// log of block weight sum: sum_{j=h}^{e} (N-j), exact integer (< 2^22)
__device__ __forceinline__ float lwf(int h, int e) {
    int s = ((N - h) + (N - e)) * (e - h + 1) / 2;
    return logf((float)s);
}

// ============================================================================
// Kernel 1: per-row bitonic sort (descending) of theta = x*10, with index.
// Writes sorted values + u16 original indices to workspace.
// rid in [0, 2*B): phase = rid / B (x1 vs x2)
// ============================================================================
__global__ void __launch_bounds__(NT)
sort_kernel(const float* __restrict__ x1, const float* __restrict__ x2,
            int nrows, float* __restrict__ ss, unsigned short* __restrict__ sidx)
{
    __shared__ float s_key[N];
    __shared__ int   s_idx[N];

    const int rid = blockIdx.x;
    const int tid = threadIdx.x;
    const float* __restrict__ x = (rid < nrows) ? x1 : x2;
    const size_t base = (size_t)(rid < nrows ? rid : rid - nrows) * N;

    for (int j = tid; j < N; j += NT) {
        s_key[j] = x[base + j] * 10.0f;
        s_idx[j] = j;
    }
    __syncthreads();

    for (int k = 2; k <= N; k <<= 1) {
        for (int jj = k >> 1; jj > 0; jj >>= 1) {
            for (int i = tid; i < N; i += NT) {
                int l = i ^ jj;
                if (l > i) {
                    float ki = s_key[i], kl = s_key[l];
                    bool sw = ((i & k) == 0) ? (ki < kl) : (ki > kl);
                    if (sw) {
                        s_key[i] = kl; s_key[l] = ki;
                        int t = s_idx[i]; s_idx[i] = s_idx[l]; s_idx[l] = t;
                    }
                }
            }
            __syncthreads();
        }
    }

    float* __restrict__ so = ss + (size_t)rid * N;
    unsigned short* __restrict__ io = sidx + (size_t)rid * N;
    for (int j = tid; j < N; j += NT) {
        so[j] = s_key[j];
        io[j] = (unsigned short)s_idx[j];
    }
}

// ============================================================================
// Kernel 2: one block (1 wave) per (row,phase). Serial PAV on lane 0 with
// 12 KB LDS state (ly fp32 + tgt u16); lw computed exactly on the fly.
// Then all 64 lanes expand sol and scatter ranks to original order.
// ============================================================================
__global__ void __launch_bounds__(64)
pav_kernel(const float* __restrict__ ss, const unsigned short* __restrict__ sidx,
           float* __restrict__ ranks)
{
    __shared__ float          s_ly[N];
    __shared__ unsigned short s_tgt[N];
    __shared__ int            s_nb;

    const int rid = blockIdx.x;
    const int t   = threadIdx.x;
    const float* __restrict__ srow = ss + (size_t)rid * N;

    for (int j = t; j < N; j += 64) {
        s_ly[j]  = srow[j];
        s_tgt[j] = (unsigned short)j;
    }
    __syncthreads();

    if (t == 0) {
        // ---- serial PAV (literal port of fast-soft-sort isotonic_kl; lw exact) ----
        int   i = 0, e_i = 0;
        float ly_i  = s_ly[0];
        float sol_i = ly_i - lwf(0, 0);
        for (;;) {
            int k = e_i + 1;
            if (k >= N) break;
            int   e_k  = s_tgt[k];
            float ly_k = s_ly[k];
            float sol_k = ly_k - lwf(k, e_k);
            if (sol_i > sol_k) {            // strictly decreasing: advance
                i = k; e_i = e_k; ly_i = ly_k; sol_i = sol_k;
                continue;
            }
            const float sol_prev = sol_i;   // anchor, fixed for this cascade
            for (;;) {
                // pool block k into block i
                ly_i  = lae(ly_i, ly_k);
                e_i   = e_k;
                sol_i = ly_i - lwf(i, e_i);
                int kn = e_i + 1;
                bool stop;
                int e_kn = 0; float ly_kn = 0.f;
                if (kn >= N) {
                    stop = true;
                } else {
                    e_kn  = s_tgt[kn];
                    ly_kn = s_ly[kn];
                    stop  = sol_prev > (ly_kn - lwf(kn, e_kn));
                }
                if (stop) {
                    s_ly[i]    = ly_i;
                    s_tgt[i]   = (unsigned short)e_i;   // head -> end
                    s_tgt[e_i] = (unsigned short)i;     // end  -> head
                    if (i > 0) {                        // backtrack to previous head
                        i     = s_tgt[i - 1];
                        e_i   = s_tgt[i];
                        ly_i  = s_ly[i];
                        sol_i = ly_i - lwf(i, e_i);
                    }
                    break;
                }
                k = kn; e_k = e_kn; ly_k = ly_kn;
            }
        }
        // ---- compact block heads in-place into s_tgt[0..nb) (ascending) ----
        int nb = 0, h = 0;
        while (h < N) {
            int e  = s_tgt[h];
            int hh = h;
            h = e + 1;
            s_tgt[nb++] = (unsigned short)hh;
        }
        s_nb = nb;
    }
    __syncthreads();

    // ---- expand sol, compute ranks, scatter to original positions ----
    const int nb = s_nb;
    const unsigned short* __restrict__ irow = sidx + (size_t)rid * N;
    float* __restrict__ rrow = ranks + (size_t)rid * N;
    for (int j = t; j < N; j += 64) {
        int lo = 0, hi = nb - 1;
        while (lo < hi) {                   // largest b with head[b] <= j
            int mid = (lo + hi + 1) >> 1;
            if ((int)s_tgt[mid] <= j) lo = mid; else hi = mid - 1;
        }
        int h = s_tgt[lo];
        int e = (lo + 1 < nb) ? ((int)s_tgt[lo + 1] - 1) : (N - 1);
        float sol = s_ly[h] - lwf(h, e);
        float r   = expf(srow[j] - sol);
        rrow[irow[j]] = r;
    }
}

// ============================================================================
// Kernel 3: correlation over row pairs -> out = 1 - corr
// ============================================================================
__global__ void __launch_bounds__(NT)
corr_kernel(const float* __restrict__ ranks, int nrows, float* __restrict__ out)
{
    __shared__ float s_red[NT / 64][5];
    const int row = blockIdx.x;
    const int tid = threadIdx.x;
    const float* __restrict__ r1 = ranks + (size_t)row * N;
    const float* __restrict__ r2 = ranks + (size_t)(row + nrows) * N;

    float S1 = 0.f, Q1 = 0.f, S2 = 0.f, Q2 = 0.f, P = 0.f;
    for (int j = tid; j < N; j += NT) {
        float a = r1[j], b = r2[j];
        S1 += a; Q1 += a * a;
        S2 += b; Q2 += b * b;
        P  += a * b;
    }
    #pragma unroll
    for (int off = 32; off > 0; off >>= 1) {
        S1 += __shfl_down(S1, off);
        Q1 += __shfl_down(Q1, off);
        S2 += __shfl_down(S2, off);
        Q2 += __shfl_down(Q2, off);
        P  += __shfl_down(P,  off);
    }
    const int wid = tid >> 6, lane = tid & 63;
    if (lane == 0) {
        s_red[wid][0] = S1; s_red[wid][1] = Q1; s_red[wid][2] = S2;
        s_red[wid][3] = Q2; s_red[wid][4] = P;
    }
    __syncthreads();
    if (tid == 0) {
        for (int w = 1; w < NT / 64; ++w) {
            S1 += s_red[w][0]; Q1 += s_red[w][1]; S2 += s_red[w][2];
            Q2 += s_red[w][3]; P  += s_red[w][4];
        }
        const float inv_n = 1.0f / (float)N;
        float num = P  - S1 * S2 * inv_n;
        float d1  = Q1 - S1 * S1 * inv_n;
        float d2  = Q2 - S2 * S2 * inv_n;
        out[row] = 1.0f - num / sqrtf(d1 * d2);
    }
}

// ============================================================================
// Fallback: validated monolithic kernel from round 1 (used if ws too small)
// ============================================================================
__global__ void __launch_bounds__(NT)
soft_spearman_mono(const float* __restrict__ x1,
                   const float* __restrict__ x2,
                   float* __restrict__ out)
{
    __shared__ float s_key[N];
    __shared__ int   s_idx[N];
    __shared__ float s_r1[N];
    __shared__ float s_ly[N];
    __shared__ float s_lw[N];
    __shared__ float s_sol[N];
    __shared__ int   s_tgt[N];
    __shared__ int   s_nb;
    __shared__ float s_red[NT / 64][5];

    const int row = blockIdx.x;
    const int tid = threadIdx.x;

    float S1 = 0.f, Q1 = 0.f, S2 = 0.f, Q2 = 0.f, P = 0.f;

    for (int phase = 0; phase < 2; ++phase) {
        const float* __restrict__ x = (phase == 0) ? x1 : x2;
        const size_t base = (size_t)row * N;

        for (int j = tid; j < N; j += NT) {
            s_key[j] = x[base + j] * 10.0f;
            s_idx[j] = j;
        }
        __syncthreads();

        for (int k = 2; k <= N; k <<= 1) {
            for (int jj = k >> 1; jj > 0; jj >>= 1) {
                for (int i = tid; i < N; i += NT) {
                    int l = i ^ jj;
                    if (l > i) {
                        float ki = s_key[i], kl = s_key[l];
                        bool sw = ((i & k) == 0) ? (ki < kl) : (ki > kl);
                        if (sw) {
                            s_key[i] = kl; s_key[l] = ki;
                            int t = s_idx[i]; s_idx[i] = s_idx[l]; s_idx[l] = t;
                        }
                    }
                }
                __syncthreads();
            }
        }

        for (int j = tid; j < N; j += NT) {
            float y = s_key[j];
            float w = logf((float)(N - j));
            s_ly[j]  = y;
            s_lw[j]  = w;
            s_sol[j] = y - w;
            s_tgt[j] = j;
        }
        __syncthreads();

        if (tid == 0) {
            int i = 0;
            while (i < N) {
                int k = s_tgt[i] + 1;
                if (k >= N) break;
                if (s_sol[i] > s_sol[k]) { i = k; continue; }
                float sol_prev = s_sol[i];
                for (;;) {
                    float ly = lae(s_ly[i], s_ly[k]);
                    float lw = lae(s_lw[i], s_lw[k]);
                    s_ly[i] = ly; s_lw[i] = lw; s_sol[i] = ly - lw;
                    int kn = s_tgt[k] + 1;
                    if (kn >= N || sol_prev > s_sol[kn]) {
                        s_tgt[i] = kn - 1;
                        s_tgt[kn - 1] = i;
                        if (i > 0) i = s_tgt[i - 1];
                        break;
                    }
                    k = kn;
                }
            }
            int nb = 0, h = 0;
            while (h < N) {
                int e  = s_tgt[h];
                int hh = h;
                h = e + 1;
                s_tgt[nb++] = hh;
            }
            s_nb = nb;
        }
        __syncthreads();

        const int nb = s_nb;
        for (int j = tid; j < N; j += NT) {
            int lo = 0, hi = nb - 1;
            while (lo < hi) {
                int mid = (lo + hi + 1) >> 1;
                if (s_tgt[mid] <= j) lo = mid; else hi = mid - 1;
            }
            float r = expf(s_key[j] - s_sol[s_tgt[lo]]);
            int   v = s_idx[j];
            if (phase == 0) {
                s_r1[v] = r;
                S1 += r; Q1 += r * r;
            } else {
                float a = s_r1[v];
                S2 += r; Q2 += r * r; P += a * r;
            }
        }
        __syncthreads();
    }

    #pragma unroll
    for (int off = 32; off > 0; off >>= 1) {
        S1 += __shfl_down(S1, off);
        Q1 += __shfl_down(Q1, off);
        S2 += __shfl_down(S2, off);
        Q2 += __shfl_down(Q2, off);
        P  += __shfl_down(P,  off);
    }
    const int wid = tid >> 6, lane = tid & 63;
    if (lane == 0) {
        s_red[wid][0] = S1; s_red[wid][1] = Q1; s_red[wid][2] = S2;
        s_red[wid][3] = Q2; s_red[wid][4] = P;
    }
    __syncthreads();
    if (tid == 0) {
        for (int w = 1; w < NT / 64; ++w) {
            S1 += s_red[w][0]; Q1 += s_red[w][1]; S2 += s_red[w][2];
            Q2 += s_red[w][3]; P  += s_red[w][4];
        }
        const float inv_n = 1.0f / (float)N;
        float num = P  - S1 * S2 * inv_n;
        float d1  = Q1 - S1 * S1 * inv_n;
        float d2  = Q2 - S2 * S2 * inv_n;
        out[row] = 1.0f - num / sqrtf(d1 * d2);
    }
}

extern "C" void kernel_launch(void* const* d_in, const int* in_sizes, int n_in,
                              void* d_out, int out_size, void* d_ws, size_t ws_size,
                              hipStream_t stream) {
    const float* x1 = (const float*)d_in[0];
    const float* x2 = (const float*)d_in[1];
    float* out = (float*)d_out;
    const int nrows = in_sizes[0] / N;        // 4096
    const int total = 2 * nrows;              // 8192 (row,phase) pairs

    const size_t SZ_S = (size_t)total * N * sizeof(float);          // sorted values
    const size_t SZ_I = (size_t)total * N * sizeof(unsigned short); // sorted indices
    const size_t SZ_R = (size_t)total * N * sizeof(float);          // ranks
    const size_t need = SZ_S + SZ_I + SZ_R;

    if (ws_size >= need) {
        float*          ss    = (float*)d_ws;
        unsigned short* sidx  = (unsigned short*)((char*)d_ws + SZ_S);
        float*          ranks = (float*)((char*)d_ws + SZ_S + SZ_I);

        sort_kernel<<<total, NT, 0, stream>>>(x1, x2, nrows, ss, sidx);
        pav_kernel<<<total, 64, 0, stream>>>(ss, sidx, ranks);
        corr_kernel<<<nrows, NT, 0, stream>>>(ranks, nrows, out);
    } else {
        soft_spearman_mono<<<nrows, NT, 0, stream>>>(x1, x2, out);
    }
}

// Round 3
// 2043.951 us; speedup vs baseline: 4.5381x; 1.2512x over previous
//
#include <hip/hip_runtime.h>
#include <math.h>

#define N   2048
#define NT  256

// stable logaddexp (fallback kernel only)
__device__ __forceinline__ float lae(float a, float b) {
    float m  = fmaxf(a, b);
    float mn = fminf(a, b);
    return m + log1pf(expf(mn - m));
}

// exact integer block weight: sum_{j=h}^{e} (N-j)
__device__ __forceinline__ int wsum(int h, int e) {
    return (((N - h) + (N - e)) * (e - h + 1)) >> 1;
}

// ============================================================================
// Kernel 1: per-row bitonic sort, packed u64 (desc-sortable key | index).
// Stable: ties broken by ascending original index == jnp.argsort(-theta).
// ============================================================================
__global__ void __launch_bounds__(NT)
sort_kernel(const float* __restrict__ x1, const float* __restrict__ x2,
            int nrows, float* __restrict__ ss, unsigned short* __restrict__ sidx)
{
    __shared__ unsigned long long s_kv[N];   // 16 KB

    const int rid = blockIdx.x;
    const int tid = threadIdx.x;
    const float* __restrict__ x = (rid < nrows) ? x1 : x2;
    const size_t base = (size_t)(rid < nrows ? rid : rid - nrows) * N;

    for (int j = tid; j < N; j += NT) {
        float th = x[base + j] * 10.0f;              // theta = x / EPS
        unsigned int u = __float_as_uint(th);
        unsigned int a = (u & 0x80000000u) ? ~u : (u ^ 0x80000000u); // asc-sortable
        s_kv[j] = ((unsigned long long)(~a) << 32) | (unsigned int)j; // desc key
    }
    __syncthreads();

    for (int k = 2; k <= N; k <<= 1) {
        for (int jj = k >> 1; jj > 0; jj >>= 1) {
            for (int i = tid; i < N; i += NT) {
                int l = i ^ jj;
                if (l > i) {
                    unsigned long long a = s_kv[i], b = s_kv[l];
                    unsigned long long mn = (a < b) ? a : b;
                    unsigned long long mx = (a < b) ? b : a;
                    bool up = ((i & k) == 0);
                    s_kv[i] = up ? mn : mx;          // ascending by kv = descending theta
                    s_kv[l] = up ? mx : mn;
                }
            }
            __syncthreads();
        }
    }

    float* __restrict__ so = ss + (size_t)rid * N;
    unsigned short* __restrict__ io = sidx + (size_t)rid * N;
    for (int j = tid; j < N; j += NT) {
        unsigned long long kv = s_kv[j];
        unsigned int a = ~(unsigned int)(kv >> 32);
        unsigned int u = (a & 0x80000000u) ? (a ^ 0x80000000u) : ~a;
        so[j] = __uint_as_float(u);
        io[j] = (unsigned short)(kv & 0xFFFFu);
    }
}

// ============================================================================
// Kernel 2: exp-domain stack PAV. One wave per (row,phase).
// Pool:  Y += Y (fp32 add), W += W (exact int).
// Order: sol_t > sol_c  <=>  Y_t * W_c > Y_c * W_t   (all positive)
// The final stack IS the ascending head list (no compaction pass).
// ============================================================================
__global__ void __launch_bounds__(64)
pav_kernel(const float* __restrict__ ss, const unsigned short* __restrict__ sidx,
           float* __restrict__ ranks)
{
    __shared__ float          s_s[N];    // sorted theta            (8 KB)
    __shared__ float          st_Y[N];   // stack: pooled Y         (8 KB)
    __shared__ unsigned short st_h[N];   // stack: block heads      (4 KB)
    __shared__ int            s_sp;

    const int rid = blockIdx.x;
    const int t   = threadIdx.x;
    const float* __restrict__ srow = ss + (size_t)rid * N;

    for (int j = t; j < N; j += 64) s_s[j] = srow[j];
    __syncthreads();

    if (t == 0) {
        int   sp   = 0;
        int   t_h  = 0;            // cached top-of-stack (valid when sp > 0)
        int   t_Wi = 0;
        float t_Y  = 0.f;
        float t_Wf = 0.f;
        for (int j = 0; j < N; ++j) {
            float E   = __expf(s_s[j]);
            float cY  = E;
            int   cW  = N - j;
            int   ch  = j;
            float cWf = (float)cW;
            while (sp > 0) {
                if (t_Y * cWf > cY * t_Wf) break;   // strictly decreasing: stop
                // pool top into cur
                cY += t_Y;
                cW += t_Wi;
                ch  = t_h;
                cWf = (float)cW;
                --sp;
                if (sp > 0) {                        // reload new top
                    t_h = st_h[sp - 1];
                    t_Y = st_Y[sp - 1];
                    t_Wi = wsum(t_h, ch - 1);        // end = cur head - 1 (contiguity)
                    t_Wf = (float)t_Wi;
                }
            }
            st_h[sp] = (unsigned short)ch;
            st_Y[sp] = cY;
            ++sp;
            t_h = ch; t_Y = cY; t_Wi = cW; t_Wf = cWf;
        }
        s_sp = sp;
    }
    __syncthreads();

    // ---- expansion: r = exp(s) * W_block / Y_block, scatter to original order
    const int nb = s_sp;
    const unsigned short* __restrict__ irow = sidx + (size_t)rid * N;
    float* __restrict__ rrow = ranks + (size_t)rid * N;
    for (int j = t; j < N; j += 64) {
        int lo = 0, hi = nb - 1;
        while (lo < hi) {                   // largest b with head[b] <= j
            int mid = (lo + hi + 1) >> 1;
            if ((int)st_h[mid] <= j) lo = mid; else hi = mid - 1;
        }
        int h = st_h[lo];
        int e = (lo + 1 < nb) ? ((int)st_h[lo + 1] - 1) : (N - 1);
        float W = (float)wsum(h, e);
        float r = __expf(s_s[j]) * W / st_Y[lo];
        rrow[irow[j]] = r;
    }
}

// ============================================================================
// Kernel 3: correlation over row pairs -> out = 1 - corr
// ============================================================================
__global__ void __launch_bounds__(NT)
corr_kernel(const float* __restrict__ ranks, int nrows, float* __restrict__ out)
{
    __shared__ float s_red[NT / 64][5];
    const int row = blockIdx.x;
    const int tid = threadIdx.x;
    const float* __restrict__ r1 = ranks + (size_t)row * N;
    const float* __restrict__ r2 = ranks + (size_t)(row + nrows) * N;

    float S1 = 0.f, Q1 = 0.f, S2 = 0.f, Q2 = 0.f, P = 0.f;
    for (int j = tid; j < N; j += NT) {
        float a = r1[j], b = r2[j];
        S1 += a; Q1 += a * a;
        S2 += b; Q2 += b * b;
        P  += a * b;
    }
    #pragma unroll
    for (int off = 32; off > 0; off >>= 1) {
        S1 += __shfl_down(S1, off);
        Q1 += __shfl_down(Q1, off);
        S2 += __shfl_down(S2, off);
        Q2 += __shfl_down(Q2, off);
        P  += __shfl_down(P,  off);
    }
    const int wid = tid >> 6, lane = tid & 63;
    if (lane == 0) {
        s_red[wid][0] = S1; s_red[wid][1] = Q1; s_red[wid][2] = S2;
        s_red[wid][3] = Q2; s_red[wid][4] = P;
    }
    __syncthreads();
    if (tid == 0) {
        for (int w = 1; w < NT / 64; ++w) {
            S1 += s_red[w][0]; Q1 += s_red[w][1]; S2 += s_red[w][2];
            Q2 += s_red[w][3]; P  += s_red[w][4];
        }
        const float inv_n = 1.0f / (float)N;
        float num = P  - S1 * S2 * inv_n;
        float d1  = Q1 - S1 * S1 * inv_n;
        float d2  = Q2 - S2 * S2 * inv_n;
        out[row] = 1.0f - num / sqrtf(d1 * d2);
    }
}

// ============================================================================
// Fallback: validated monolithic kernel (used only if ws too small)
// ============================================================================
__global__ void __launch_bounds__(NT)
soft_spearman_mono(const float* __restrict__ x1,
                   const float* __restrict__ x2,
                   float* __restrict__ out)
{
    __shared__ float s_key[N];
    __shared__ int   s_idx[N];
    __shared__ float s_r1[N];
    __shared__ float s_ly[N];
    __shared__ float s_lw[N];
    __shared__ float s_sol[N];
    __shared__ int   s_tgt[N];
    __shared__ int   s_nb;
    __shared__ float s_red[NT / 64][5];

    const int row = blockIdx.x;
    const int tid = threadIdx.x;

    float S1 = 0.f, Q1 = 0.f, S2 = 0.f, Q2 = 0.f, P = 0.f;

    for (int phase = 0; phase < 2; ++phase) {
        const float* __restrict__ x = (phase == 0) ? x1 : x2;
        const size_t base = (size_t)row * N;

        for (int j = tid; j < N; j += NT) {
            s_key[j] = x[base + j] * 10.0f;
            s_idx[j] = j;
        }
        __syncthreads();

        for (int k = 2; k <= N; k <<= 1) {
            for (int jj = k >> 1; jj > 0; jj >>= 1) {
                for (int i = tid; i < N; i += NT) {
                    int l = i ^ jj;
                    if (l > i) {
                        float ki = s_key[i], kl = s_key[l];
                        bool sw = ((i & k) == 0) ? (ki < kl) : (ki > kl);
                        if (sw) {
                            s_key[i] = kl; s_key[l] = ki;
                            int t = s_idx[i]; s_idx[i] = s_idx[l]; s_idx[l] = t;
                        }
                    }
                }
                __syncthreads();
            }
        }

        for (int j = tid; j < N; j += NT) {
            float y = s_key[j];
            float w = logf((float)(N - j));
            s_ly[j]  = y;
            s_lw[j]  = w;
            s_sol[j] = y - w;
            s_tgt[j] = j;
        }
        __syncthreads();

        if (tid == 0) {
            int i = 0;
            while (i < N) {
                int k = s_tgt[i] + 1;
                if (k >= N) break;
                if (s_sol[i] > s_sol[k]) { i = k; continue; }
                float sol_prev = s_sol[i];
                for (;;) {
                    float ly = lae(s_ly[i], s_ly[k]);
                    float lw = lae(s_lw[i], s_lw[k]);
                    s_ly[i] = ly; s_lw[i] = lw; s_sol[i] = ly - lw;
                    int kn = s_tgt[k] + 1;
                    if (kn >= N || sol_prev > s_sol[kn]) {
                        s_tgt[i] = kn - 1;
                        s_tgt[kn - 1] = i;
                        if (i > 0) i = s_tgt[i - 1];
                        break;
                    }
                    k = kn;
                }
            }
            int nb = 0, h = 0;
            while (h < N) {
                int e  = s_tgt[h];
                int hh = h;
                h = e + 1;
                s_tgt[nb++] = hh;
            }
            s_nb = nb;
        }
        __syncthreads();

        const int nb = s_nb;
        for (int j = tid; j < N; j += NT) {
            int lo = 0, hi = nb - 1;
            while (lo < hi) {
                int mid = (lo + hi + 1) >> 1;
                if (s_tgt[mid] <= j) lo = mid; else hi = mid - 1;
            }
            float r = expf(s_key[j] - s_sol[s_tgt[lo]]);
            int   v = s_idx[j];
            if (phase == 0) {
                s_r1[v] = r;
                S1 += r; Q1 += r * r;
            } else {
                float a = s_r1[v];
                S2 += r; Q2 += r * r; P += a * r;
            }
        }
        __syncthreads();
    }

    #pragma unroll
    for (int off = 32; off > 0; off >>= 1) {
        S1 += __shfl_down(S1, off);
        Q1 += __shfl_down(Q1, off);
        S2 += __shfl_down(S2, off);
        Q2 += __shfl_down(Q2, off);
        P  += __shfl_down(P,  off);
    }
    const int wid = tid >> 6, lane = tid & 63;
    if (lane == 0) {
        s_red[wid][0] = S1; s_red[wid][1] = Q1; s_red[wid][2] = S2;
        s_red[wid][3] = Q2; s_red[wid][4] = P;
    }
    __syncthreads();
    if (tid == 0) {
        for (int w = 1; w < NT / 64; ++w) {
            S1 += s_red[w][0]; Q1 += s_red[w][1]; S2 += s_red[w][2];
            Q2 += s_red[w][3]; P  += s_red[w][4];
        }
        const float inv_n = 1.0f / (float)N;
        float num = P  - S1 * S2 * inv_n;
        float d1  = Q1 - S1 * S1 * inv_n;
        float d2  = Q2 - S2 * S2 * inv_n;
        out[row] = 1.0f - num / sqrtf(d1 * d2);
    }
}

extern "C" void kernel_launch(void* const* d_in, const int* in_sizes, int n_in,
                              void* d_out, int out_size, void* d_ws, size_t ws_size,
                              hipStream_t stream) {
    const float* x1 = (const float*)d_in[0];
    const float* x2 = (const float*)d_in[1];
    float* out = (float*)d_out;
    const int nrows = in_sizes[0] / N;        // 4096
    const int total = 2 * nrows;              // 8192 (row,phase) pairs

    const size_t SZ_S = (size_t)total * N * sizeof(float);          // sorted values
    const size_t SZ_I = (size_t)total * N * sizeof(unsigned short); // sorted indices
    const size_t SZ_R = (size_t)total * N * sizeof(float);          // ranks
    const size_t need = SZ_S + SZ_I + SZ_R;

    if (ws_size >= need) {
        float*          ss    = (float*)d_ws;
        unsigned short* sidx  = (unsigned short*)((char*)d_ws + SZ_S);
        float*          ranks = (float*)((char*)d_ws + SZ_S + SZ_I);

        sort_kernel<<<total, NT, 0, stream>>>(x1, x2, nrows, ss, sidx);
        pav_kernel<<<total, 64, 0, stream>>>(ss, sidx, ranks);
        corr_kernel<<<nrows, NT, 0, stream>>>(ranks, nrows, out);
    } else {
        soft_spearman_mono<<<nrows, NT, 0, stream>>>(x1, x2, out);
    }
}